// Round 2
// baseline (146.688 us; speedup 1.0000x reference)
//
#include <hip/hip_runtime.h>

// Problem constants (match reference setup_inputs).
#define BB 4
#define CC 128
#define CE 64
#define VV 4096
#define NLEV 14   // MAX_LEVELS

// Workspace layout (all per-batch stride VV):
//   gi     [BB*VV] int   : gi[k]  = sorted_index[levelorder[k]]  (original pixel id)
//   cpk    [BB*VV] int   : cpk[k] = levelpos of parent of node at levelpos k
//   wl     [BB*VV] float : wl[k]  = edge weight of node at levelpos k
//   posnrm [BB*VV] f/i   : K0/K1 phase: pos[i] (sortedpos -> levelpos);
//                          K2/K3 phase: invnrm[k] = 1/nrm_final  (overlaid, safe: serial stream)
//   offs   [BB*16] int   : level start offsets (0..NLEV)

__device__ __forceinline__ void lds_fadd(float* p, float v) {
    unsafeAtomicAdd(p, v);   // ds_add_f32 on gfx950 LDS
}

// ---------------------------------------------------------------------------
// K0: per-batch counting sort by level + level-position remap tables.
// ---------------------------------------------------------------------------
__global__ __launch_bounds__(256) void sort_kernel(
    const int* __restrict__ sorted_index,
    const int* __restrict__ sorted_parent,
    const int* __restrict__ node_level,
    int* __restrict__ gi,
    int* __restrict__ cpk,
    int* __restrict__ pos,        // posnrm as int during prep
    int* __restrict__ offs)
{
    __shared__ int pos_s[VV];
    __shared__ int hist[NLEV + 1];
    __shared__ int cursor[NLEV];
    int b = blockIdx.x, tid = threadIdx.x;
    const int* lev = node_level   + b * VV;
    const int* si  = sorted_index + b * VV;
    const int* par = sorted_parent+ b * VV;

    if (tid < NLEV + 1) hist[tid] = 0;
    __syncthreads();
    for (int i = tid; i < VV; i += 256) atomicAdd(&hist[lev[i]], 1);
    __syncthreads();
    if (tid == 0) {
        int acc = 0;
        for (int d = 0; d < NLEV; ++d) { int h = hist[d]; hist[d] = acc; cursor[d] = acc; acc += h; }
        hist[NLEV] = acc;
    }
    __syncthreads();
    if (tid <= NLEV) offs[b * 16 + tid] = hist[tid];
    for (int i = tid; i < VV; i += 256) {
        int k = atomicAdd(&cursor[lev[i]], 1);
        pos_s[i] = k;
        pos[b * VV + i] = k;
        gi[b * VV + k] = si[i];
    }
    __syncthreads();
    for (int i = tid; i < VV; i += 256) {
        cpk[b * VV + pos_s[i]] = pos_s[par[i]];
    }
}

// ---------------------------------------------------------------------------
// K1: edge weights. One 64-lane wave per node, lane = embed channel.
//     w = exp(-||e[:,vi] - e[:,vp]||^2), written at levelpos.
// ---------------------------------------------------------------------------
__global__ __launch_bounds__(256) void weight_kernel(
    const float* __restrict__ embed,
    const int* __restrict__ sorted_index,
    const int* __restrict__ sorted_parent,
    const int* __restrict__ pos,
    float* __restrict__ wl)
{
    int lane = threadIdx.x & 63;
    int g = blockIdx.x * 4 + (threadIdx.x >> 6);   // node id in [0, BB*VV)
    int b = g >> 12;                                // VV = 4096
    int i = g & (VV - 1);
    int vi = sorted_index[b * VV + i];
    int p  = sorted_parent[b * VV + i];
    int vp = sorted_index[b * VV + p];
    const float* eb = embed + (size_t)b * CE * VV;
    float diff = eb[(size_t)lane * VV + vi] - eb[(size_t)lane * VV + vp];
    float d2 = diff * diff;
    #pragma unroll
    for (int o = 32; o > 0; o >>= 1) d2 += __shfl_xor(d2, o, 64);
    if (lane == 0) wl[b * VV + pos[b * VV + i]] = __expf(-d2);
}

// ---------------------------------------------------------------------------
// K2: normalizer chain (channel-independent) once per batch. 26 barrier
//     phases but only 4 blocks. Emits invnrm[k] = 1/nrm_final.
// ---------------------------------------------------------------------------
__global__ __launch_bounds__(256) void nrm_kernel(
    const int* __restrict__ cpk,
    const float* __restrict__ wl,
    const int* __restrict__ offs,
    float* __restrict__ invnrm)   // posnrm as float now (pos no longer needed)
{
    __shared__ float vn[VV];
    int b = blockIdx.x, tid = threadIdx.x;
    const int*   cp  = cpk + b * VV;
    const float* w   = wl  + b * VV;
    const int*   off = offs+ b * 16;

    for (int k = tid; k < VV; k += 256) vn[k] = 1.0f;
    __syncthreads();
    for (int d = NLEV - 1; d >= 1; --d) {
        int e = off[d + 1];
        for (int k = off[d] + tid; k < e; k += 256)
            lds_fadd(&vn[cp[k]], w[k] * vn[k]);
        __syncthreads();
    }
    for (int d = 1; d <= NLEV - 1; ++d) {
        int e = off[d + 1];
        for (int k = off[d] + tid; k < e; k += 256) {
            float u = vn[k], wk = w[k];
            vn[k] = fmaf(wk, vn[cp[k]] - wk * u, u);
        }
        __syncthreads();
    }
    for (int k = tid; k < VV; k += 256) invnrm[b * VV + k] = 1.0f / vn[k];
}

// ---------------------------------------------------------------------------
// K3: per-(b,c) tree filter. ONE WAVE per block -> no s_barrier at all;
//     level boundaries only need s_waitcnt lgkmcnt(0) (DS completion).
//     val[] indexed by level position: own-node accesses are linear.
// ---------------------------------------------------------------------------
__global__ __launch_bounds__(64) void tree_kernel(
    const float* __restrict__ feat,
    const int* __restrict__ gi,
    const int* __restrict__ cpk,
    const float* __restrict__ wl,
    const float* __restrict__ invnrm,
    const int* __restrict__ offs,
    float* __restrict__ out)
{
    __shared__ float val[VV];
    int blk = blockIdx.x;
    int b = blk >> 7;          // CC = 128
    int c = blk & (CC - 1);
    int lane = threadIdx.x;

    const int*   g   = gi     + b * VV;
    const int*   cp  = cpk    + b * VV;
    const float* w   = wl     + b * VV;
    const float* inr = invnrm + b * VV;
    const int*   off = offs   + b * 16;
    const float* f   = feat + ((size_t)(b * CC + c)) * VV;

    // init: val[k] = f[gi[k]]  (scattered global gather, pipelined)
    #pragma unroll 8
    for (int k = lane; k < VV; k += 64) val[k] = f[g[k]];
    __asm__ volatile("s_waitcnt lgkmcnt(0)" ::: "memory");

    // upward: deepest level first; single wave => DS-completion wait only
    for (int d = NLEV - 1; d >= 1; --d) {
        int e = off[d + 1];
        for (int k = off[d] + lane; k < e; k += 64)
            lds_fadd(&val[cp[k]], w[k] * val[k]);
        __asm__ volatile("s_waitcnt lgkmcnt(0)" ::: "memory");
    }

    // downward: in place; level-d writes never alias level-(d-1) parent reads
    for (int d = 1; d <= NLEV - 1; ++d) {
        int e = off[d + 1];
        for (int k = off[d] + lane; k < e; k += 64) {
            float u = val[k], wk = w[k];
            val[k] = fmaf(wk, val[cp[k]] - wk * u, u);
        }
        __asm__ volatile("s_waitcnt lgkmcnt(0)" ::: "memory");
    }

    // normalize + unsort scatter
    float* ob = out + ((size_t)(b * CC + c)) * VV;
    #pragma unroll 4
    for (int k = lane; k < VV; k += 64) ob[g[k]] = val[k] * inr[k];
}

extern "C" void kernel_launch(void* const* d_in, const int* in_sizes, int n_in,
                              void* d_out, int out_size, void* d_ws, size_t ws_size,
                              hipStream_t stream) {
    const float* feat          = (const float*)d_in[0];
    const float* embed         = (const float*)d_in[1];
    const int*   sorted_index  = (const int*)d_in[2];
    const int*   sorted_parent = (const int*)d_in[3];
    const int*   node_level    = (const int*)d_in[4];
    float* out = (float*)d_out;

    char* ws = (char*)d_ws;
    const size_t A = (size_t)BB * VV * 4;   // 64 KB per array
    int*   gi     = (int*)  (ws);
    int*   cpk    = (int*)  (ws + A);
    float* wl     = (float*)(ws + 2 * A);
    void*  posnrm = (void*) (ws + 3 * A);   // pos (prep) then invnrm (overlaid)
    int*   offs   = (int*)  (ws + 4 * A);

    sort_kernel<<<BB, 256, 0, stream>>>(
        sorted_index, sorted_parent, node_level, gi, cpk, (int*)posnrm, offs);

    weight_kernel<<<(BB * VV) / 4, 256, 0, stream>>>(
        embed, sorted_index, sorted_parent, (const int*)posnrm, wl);

    nrm_kernel<<<BB, 256, 0, stream>>>(
        cpk, wl, offs, (float*)posnrm);

    tree_kernel<<<BB * CC, 64, 0, stream>>>(
        feat, gi, cpk, wl, (const float*)posnrm, offs, out);
}

// Round 3
// 127.292 us; speedup vs baseline: 1.1524x; 1.1524x over previous
//
#include <hip/hip_runtime.h>

// Problem constants (match reference setup_inputs).
#define BB 4
#define CC 128
#define CE 64
#define VV 4096
#define NLEV 14   // MAX_LEVELS

// Workspace layout:
//   gi   [BB*VV] int          : pixel id of node at levelpos k
//   gp   [BB*VV] int          : pixel id of PARENT of node at levelpos k
//   pw   [BB*2*VV] int/float  : interleaved {cp(levelpos of parent), w(bits)}
//   offs [BB*16] int          : level start offsets
//   et   [BB*VV*CE] float     : embed transposed to [b][v][ce] (4 MB)

__device__ __forceinline__ void lds_fadd(float* p, float v) {
    unsafeAtomicAdd(p, v);   // ds_add_f32 on gfx950 LDS
}

// ---------------------------------------------------------------------------
// K_A: blocks [0,BB): per-batch counting sort (levelpos remap, parent tables)
//      blocks [BB, BB+BB*64): 64x64 tile transpose of embed -> et[b][v][ce]
// ---------------------------------------------------------------------------
__global__ __launch_bounds__(256) void prep_kernel(
    const float* __restrict__ embed,
    const int* __restrict__ sorted_index,
    const int* __restrict__ sorted_parent,
    const int* __restrict__ node_level,
    int* __restrict__ gi,
    int* __restrict__ gp,
    int* __restrict__ pw,
    int* __restrict__ offs,
    float* __restrict__ et,
    int do_transpose)
{
    int tid = threadIdx.x;
    if (blockIdx.x < BB) {
        int b = blockIdx.x;
        __shared__ int pos_s[VV];
        __shared__ int si_s[VV];
        __shared__ int hist[NLEV + 1];
        __shared__ int cursor[NLEV];
        const int* lev = node_level    + b * VV;
        const int* si  = sorted_index  + b * VV;
        const int* par = sorted_parent + b * VV;

        if (tid < NLEV + 1) hist[tid] = 0;
        __syncthreads();
        for (int i = tid; i < VV; i += 256) {
            si_s[i] = si[i];
            int d = lev[i]; d = d < NLEV - 1 ? d : NLEV - 1;
            atomicAdd(&hist[d], 1);
        }
        __syncthreads();
        if (tid == 0) {
            int acc = 0;
            for (int d = 0; d < NLEV; ++d) { int h = hist[d]; hist[d] = acc; cursor[d] = acc; acc += h; }
            hist[NLEV] = acc;
        }
        __syncthreads();
        if (tid <= NLEV) offs[b * 16 + tid] = hist[tid];
        for (int i = tid; i < VV; i += 256) {
            int d = lev[i]; d = d < NLEV - 1 ? d : NLEV - 1;
            int k = atomicAdd(&cursor[d], 1);
            pos_s[i] = k;
            gi[b * VV + k] = si_s[i];
        }
        __syncthreads();
        for (int i = tid; i < VV; i += 256) {
            int p = par[i];
            int k = pos_s[i];
            pw[b * 2 * VV + 2 * k] = pos_s[p];
            gp[b * VV + k] = si_s[p];
        }
    } else if (do_transpose) {
        int t  = blockIdx.x - BB;
        int b  = t >> 6;
        int v0 = (t & 63) << 6;
        __shared__ float tile[64][65];
        int vloc = tid & 63;
        int ce0  = (tid >> 6) * 16;
        const float* eb = embed + (size_t)b * CE * VV;
        #pragma unroll
        for (int r = 0; r < 16; ++r)
            tile[ce0 + r][vloc] = eb[(size_t)(ce0 + r) * VV + v0 + vloc];
        __syncthreads();
        #pragma unroll
        for (int r = 0; r < 4; ++r) {
            int v  = (tid >> 4) + r * 16;
            int c4 = (tid & 15) * 4;
            float4 val = make_float4(tile[c4][v], tile[c4+1][v], tile[c4+2][v], tile[c4+3][v]);
            *(float4*)(et + ((size_t)(b * VV) + v0 + v) * CE + c4) = val;
        }
    }
}

// ---------------------------------------------------------------------------
// K_B: edge weights from transposed embed. One wave per node; lane = channel.
//      Node's 64 channels are contiguous 256B -> fully coalesced gathers.
// ---------------------------------------------------------------------------
__global__ __launch_bounds__(256) void weight_t_kernel(
    const float* __restrict__ et,
    const int* __restrict__ gi,
    const int* __restrict__ gp,
    int* __restrict__ pw)
{
    int lane = threadIdx.x & 63;
    int g = blockIdx.x * 4 + (threadIdx.x >> 6);
    int b = g >> 12, k = g & (VV - 1);
    int vi = gi[b * VV + k];
    int vp = gp[b * VV + k];
    float a = et[((size_t)(b * VV) + vi) * CE + lane];
    float q = et[((size_t)(b * VV) + vp) * CE + lane];
    float d = a - q, d2 = d * d;
    #pragma unroll
    for (int o = 32; o > 0; o >>= 1) d2 += __shfl_xor(d2, o, 64);
    if (lane == 0) ((float*)pw)[b * 2 * VV + 2 * k + 1] = __expf(-d2);
}

// Fallback weight kernel (no workspace for et): strided embed gathers.
__global__ __launch_bounds__(256) void weight_s_kernel(
    const float* __restrict__ embed,
    const int* __restrict__ gi,
    const int* __restrict__ gp,
    int* __restrict__ pw)
{
    int lane = threadIdx.x & 63;
    int g = blockIdx.x * 4 + (threadIdx.x >> 6);
    int b = g >> 12, k = g & (VV - 1);
    int vi = gi[b * VV + k];
    int vp = gp[b * VV + k];
    const float* eb = embed + (size_t)b * CE * VV;
    float a = eb[(size_t)lane * VV + vi];
    float q = eb[(size_t)lane * VV + vp];
    float d = a - q, d2 = d * d;
    #pragma unroll
    for (int o = 32; o > 0; o >>= 1) d2 += __shfl_xor(d2, o, 64);
    if (lane == 0) ((float*)pw)[b * 2 * VV + 2 * k + 1] = __expf(-d2);
}

// ---------------------------------------------------------------------------
// K_C: per-(b,c) tree filter + fused normalizer chain. ONE WAVE per block:
//      level boundaries need only s_waitcnt, no s_barrier. All phase data
//      (cp,w) and state (val,nrm) live in LDS as interleaved b64 pairs.
// ---------------------------------------------------------------------------
__global__ __launch_bounds__(64) void tree_kernel(
    const float* __restrict__ feat,
    const int* __restrict__ gi,
    const int* __restrict__ pw,
    const int* __restrict__ offs,
    float* __restrict__ out)
{
    __shared__ float vv[2 * VV];   // interleaved {val, nrm} by levelpos (32 KB)
    __shared__ int  pwS[2 * VV];   // interleaved {cp, w-bits}         (32 KB)
    int blk  = blockIdx.x;
    int b    = blk >> 7;           // CC = 128
    int c    = blk & (CC - 1);
    int lane = threadIdx.x;

    const int*   gB  = gi + b * VV;
    const int*   pwB = pw + b * 2 * VV;
    const int*   off = offs + b * 16;
    const float* f   = feat + ((size_t)(b * CC + c)) * VV;

    // stage (cp,w) pairs: linear int4 global -> b128 LDS writes
    #pragma unroll
    for (int t = 0; t < 32; ++t) {
        int4 x = ((const int4*)pwB)[lane + t * 64];
        *(int4*)&pwS[4 * (lane + t * 64)] = x;
    }

    // init: vv[2k] = f[gi[k]] (scattered gather, pipelined), vv[2k+1] = 1
    #pragma unroll 8
    for (int k = lane; k < VV; k += 64) {
        int gk = gB[k];
        float2 p; p.x = f[gk]; p.y = 1.0f;
        *(float2*)&vv[2 * k] = p;
    }
    __asm__ volatile("s_waitcnt vmcnt(0) lgkmcnt(0)" ::: "memory");

    // upward: deepest level first; single wave => waitcnt-only level sync
    for (int d = NLEV - 1; d >= 1; --d) {
        int e = off[d + 1];
        for (int k = off[d] + lane; k < e; k += 64) {
            int2 cw = *(const int2*)&pwS[2 * k];
            int cp = cw.x; float w = __int_as_float(cw.y);
            float2 u = *(const float2*)&vv[2 * k];
            lds_fadd(&vv[2 * cp],     w * u.x);
            lds_fadd(&vv[2 * cp + 1], w * u.y);
        }
        __asm__ volatile("s_waitcnt lgkmcnt(0)" ::: "memory");
    }

    // downward: in place; parent (level d-1) is final when level d reads it
    for (int d = 1; d <= NLEV - 1; ++d) {
        int e = off[d + 1];
        for (int k = off[d] + lane; k < e; k += 64) {
            int2 cw = *(const int2*)&pwS[2 * k];
            int cp = cw.x; float w = __int_as_float(cw.y);
            float2 u  = *(const float2*)&vv[2 * k];
            float2 pa = *(const float2*)&vv[2 * cp];
            float2 r;
            r.x = fmaf(w, fmaf(-w, u.x, pa.x), u.x);
            r.y = fmaf(w, fmaf(-w, u.y, pa.y), u.y);
            *(float2*)&vv[2 * k] = r;
        }
        __asm__ volatile("s_waitcnt lgkmcnt(0)" ::: "memory");
    }

    // normalize + unsort scatter (stores are fire-and-forget)
    float* ob = out + ((size_t)(b * CC + c)) * VV;
    #pragma unroll 8
    for (int k = lane; k < VV; k += 64) {
        float2 u = *(const float2*)&vv[2 * k];
        ob[gB[k]] = u.x / u.y;
    }
}

extern "C" void kernel_launch(void* const* d_in, const int* in_sizes, int n_in,
                              void* d_out, int out_size, void* d_ws, size_t ws_size,
                              hipStream_t stream) {
    const float* feat          = (const float*)d_in[0];
    const float* embed         = (const float*)d_in[1];
    const int*   sorted_index  = (const int*)d_in[2];
    const int*   sorted_parent = (const int*)d_in[3];
    const int*   node_level    = (const int*)d_in[4];
    float* out = (float*)d_out;

    char* ws = (char*)d_ws;
    const size_t A = (size_t)BB * VV * 4;        // 64 KB
    int*   gi   = (int*)(ws);                    // 64 KB
    int*   gp   = (int*)(ws + A);                // 64 KB
    int*   pw   = (int*)(ws + 2 * A);            // 128 KB
    int*   offs = (int*)(ws + 4 * A);            // 256 B (pad to 4 KB)
    float* et   = (float*)(ws + 4 * A + 4096);   // 4 MB
    const size_t need_et = 4 * A + 4096 + (size_t)BB * VV * CE * 4;
    int use_et = (ws_size >= need_et) ? 1 : 0;

    int prep_blocks = use_et ? (BB + BB * 64) : BB;
    prep_kernel<<<prep_blocks, 256, 0, stream>>>(
        embed, sorted_index, sorted_parent, node_level, gi, gp, pw, offs, et, use_et);

    if (use_et)
        weight_t_kernel<<<(BB * VV) / 4, 256, 0, stream>>>(et, gi, gp, pw);
    else
        weight_s_kernel<<<(BB * VV) / 4, 256, 0, stream>>>(embed, gi, gp, pw);

    tree_kernel<<<BB * CC, 64, 0, stream>>>(feat, gi, pw, offs, out);
}

// Round 4
// 112.237 us; speedup vs baseline: 1.3069x; 1.1341x over previous
//
#include <hip/hip_runtime.h>

// Problem constants (match reference setup_inputs).
#define BB 4
#define CC 128
#define CE 64
#define VV 4096
#define NLEV 14   // MAX_LEVELS

// Workspace layout:
//   gi    [BB*VV] int         : pixel id of node at levelpos k
//   gp    [BB*VV] int         : pixel id of PARENT of node at levelpos k
//   giInv [BB*VV] int         : levelpos of pixel v  (inverse of gi)
//   pw    [BB*2*VV] int/float : interleaved {cp(levelpos of parent), w bits}
//   offs  [BB*16] int         : level start offsets
//   et    [BB*VV*CE] float    : embed transposed to [b][v][ce] (4 MB)

__device__ __forceinline__ void lds_fadd(float* p, float v) {
    unsafeAtomicAdd(p, v);   // ds_add_f32 on gfx950 LDS
}

// ---------------------------------------------------------------------------
// K_A: blocks [0,BB): per-batch counting sort -> levelpos tables (+inverse)
//      blocks [BB, BB+BB*64): 64x64 tile transpose of embed -> et[b][v][ce]
// ---------------------------------------------------------------------------
__global__ __launch_bounds__(256) void prep_kernel(
    const float* __restrict__ embed,
    const int* __restrict__ sorted_index,
    const int* __restrict__ sorted_parent,
    const int* __restrict__ node_level,
    int* __restrict__ gi,
    int* __restrict__ gp,
    int* __restrict__ giInv,
    int* __restrict__ pw,
    int* __restrict__ offs,
    float* __restrict__ et,
    int do_transpose)
{
    int tid = threadIdx.x;
    if (blockIdx.x < BB) {
        int b = blockIdx.x;
        __shared__ int pos_s[VV];
        __shared__ int si_s[VV];
        __shared__ int hist[NLEV + 1];
        __shared__ int cursor[NLEV];
        const int* lev = node_level    + b * VV;
        const int* si  = sorted_index  + b * VV;
        const int* par = sorted_parent + b * VV;

        if (tid < NLEV + 1) hist[tid] = 0;
        __syncthreads();
        for (int i = tid; i < VV; i += 256) {
            si_s[i] = si[i];
            int d = lev[i]; d = d < NLEV - 1 ? d : NLEV - 1;
            atomicAdd(&hist[d], 1);
        }
        __syncthreads();
        if (tid == 0) {
            int acc = 0;
            for (int d = 0; d < NLEV; ++d) { int h = hist[d]; hist[d] = acc; cursor[d] = acc; acc += h; }
            hist[NLEV] = acc;
        }
        __syncthreads();
        if (tid <= NLEV) offs[b * 16 + tid] = hist[tid];
        for (int i = tid; i < VV; i += 256) {
            int d = lev[i]; d = d < NLEV - 1 ? d : NLEV - 1;
            int k = atomicAdd(&cursor[d], 1);
            pos_s[i] = k;
            int v = si_s[i];
            gi[b * VV + k] = v;
            giInv[b * VV + v] = k;
        }
        __syncthreads();
        for (int i = tid; i < VV; i += 256) {
            int p = par[i];
            int k = pos_s[i];
            pw[b * 2 * VV + 2 * k] = pos_s[p];
            gp[b * VV + k] = si_s[p];
        }
    } else if (do_transpose) {
        int t  = blockIdx.x - BB;
        int b  = t >> 6;
        int v0 = (t & 63) << 6;
        __shared__ float tile[64][65];
        int vloc = tid & 63;
        int ce0  = (tid >> 6) * 16;
        const float* eb = embed + (size_t)b * CE * VV;
        #pragma unroll
        for (int r = 0; r < 16; ++r)
            tile[ce0 + r][vloc] = eb[(size_t)(ce0 + r) * VV + v0 + vloc];
        __syncthreads();
        #pragma unroll
        for (int r = 0; r < 4; ++r) {
            int v  = (tid >> 4) + r * 16;
            int c4 = (tid & 15) * 4;
            float4 val = make_float4(tile[c4][v], tile[c4+1][v], tile[c4+2][v], tile[c4+3][v]);
            *(float4*)(et + ((size_t)(b * VV) + v0 + v) * CE + c4) = val;
        }
    }
}

// ---------------------------------------------------------------------------
// K_B: edge weights from transposed embed. One wave per node; lane = channel.
// ---------------------------------------------------------------------------
__global__ __launch_bounds__(256) void weight_t_kernel(
    const float* __restrict__ et,
    const int* __restrict__ gi,
    const int* __restrict__ gp,
    int* __restrict__ pw)
{
    int lane = threadIdx.x & 63;
    int g = blockIdx.x * 4 + (threadIdx.x >> 6);
    int b = g >> 12, k = g & (VV - 1);
    int vi = gi[b * VV + k];
    int vp = gp[b * VV + k];
    float a = et[((size_t)(b * VV) + vi) * CE + lane];
    float q = et[((size_t)(b * VV) + vp) * CE + lane];
    float d = a - q, d2 = d * d;
    #pragma unroll
    for (int o = 32; o > 0; o >>= 1) d2 += __shfl_xor(d2, o, 64);
    if (lane == 0) ((float*)pw)[b * 2 * VV + 2 * k + 1] = __expf(-d2);
}

// Fallback (no workspace for et): strided embed gathers.
__global__ __launch_bounds__(256) void weight_s_kernel(
    const float* __restrict__ embed,
    const int* __restrict__ gi,
    const int* __restrict__ gp,
    int* __restrict__ pw)
{
    int lane = threadIdx.x & 63;
    int g = blockIdx.x * 4 + (threadIdx.x >> 6);
    int b = g >> 12, k = g & (VV - 1);
    int vi = gi[b * VV + k];
    int vp = gp[b * VV + k];
    const float* eb = embed + (size_t)b * CE * VV;
    float a = eb[(size_t)lane * VV + vi];
    float q = eb[(size_t)lane * VV + vp];
    float d = a - q, d2 = d * d;
    #pragma unroll
    for (int o = 32; o > 0; o >>= 1) d2 += __shfl_xor(d2, o, 64);
    if (lane == 0) ((float*)pw)[b * 2 * VV + 2 * k + 1] = __expf(-d2);
}

// ---------------------------------------------------------------------------
// K_C: per-(b,c) tree filter + fused normalizer. 256 threads (4 waves) per
//      block -> 8 waves/CU for latency hiding. ALL global traffic coalesced
//      (float4/int4 via the inverse permutation); scatter/gather lives in LDS.
//      vv: interleaved {val, nrm} by levelpos; pwS: interleaved {cp, w bits}.
// ---------------------------------------------------------------------------
__global__ __launch_bounds__(256) void tree_kernel(
    const float* __restrict__ feat,
    const int* __restrict__ giInv,
    const int* __restrict__ pw,
    const int* __restrict__ offs,
    float* __restrict__ out)
{
    __shared__ float vv[2 * VV];   // 32 KB
    __shared__ int  pwS[2 * VV];   // 32 KB
    __shared__ int  offS[16];
    int b   = blockIdx.x >> 7;     // CC = 128
    int c   = blockIdx.x & (CC - 1);
    int tid = threadIdx.x;

    const int*   pwB = pw    + b * 2 * VV;
    const int*   ivB = giInv + b * VV;
    const float* f   = feat + ((size_t)(b * CC + c)) * VV;

    if (tid < 16) offS[tid] = offs[b * 16 + tid];

    // stage (cp,w) pairs: coalesced int4 global -> b128 LDS
    #pragma unroll
    for (int t = 0; t < 8; ++t) {
        int idx = tid + t * 256;
        int4 x = ((const int4*)pwB)[idx];
        *(int4*)&pwS[4 * idx] = x;
    }

    // init: coalesced float4/int4 reads, scattered LDS b64 writes
    #pragma unroll
    for (int t = 0; t < 4; ++t) {
        int idx = tid + t * 256;
        float4 fv = ((const float4*)f)[idx];
        int4   kk = ((const int4*)ivB)[idx];
        float2 a; a.y = 1.0f;
        a.x = fv.x; *(float2*)&vv[2 * kk.x] = a;
        a.x = fv.y; *(float2*)&vv[2 * kk.y] = a;
        a.x = fv.z; *(float2*)&vv[2 * kk.z] = a;
        a.x = fv.w; *(float2*)&vv[2 * kk.w] = a;
    }
    __syncthreads();

    // upward: parents of level d are exactly level d-1 -> phase-safe atomics
    for (int d = NLEV - 1; d >= 1; --d) {
        int e = offS[d + 1];
        for (int k = offS[d] + tid; k < e; k += 256) {
            int2 cw = *(const int2*)&pwS[2 * k];
            float w = __int_as_float(cw.y);
            float2 u = *(const float2*)&vv[2 * k];
            lds_fadd(&vv[2 * cw.x],     w * u.x);
            lds_fadd(&vv[2 * cw.x + 1], w * u.y);
        }
        __syncthreads();
    }

    // downward: in place; parent (level d-1) final before level d reads it
    for (int d = 1; d <= NLEV - 1; ++d) {
        int e = offS[d + 1];
        for (int k = offS[d] + tid; k < e; k += 256) {
            int2 cw = *(const int2*)&pwS[2 * k];
            float w = __int_as_float(cw.y);
            float2 u  = *(const float2*)&vv[2 * k];
            float2 pa = *(const float2*)&vv[2 * cw.x];
            float2 r;
            r.x = fmaf(w, fmaf(-w, u.x, pa.x), u.x);
            r.y = fmaf(w, fmaf(-w, u.y, pa.y), u.y);
            *(float2*)&vv[2 * k] = r;
        }
        __syncthreads();
    }

    // epilogue: scattered LDS b64 reads, coalesced float4 global stores
    float* ob = out + ((size_t)(b * CC + c)) * VV;
    #pragma unroll
    for (int t = 0; t < 4; ++t) {
        int idx = tid + t * 256;
        int4 kk = ((const int4*)ivB)[idx];
        float2 u0 = *(const float2*)&vv[2 * kk.x];
        float2 u1 = *(const float2*)&vv[2 * kk.y];
        float2 u2 = *(const float2*)&vv[2 * kk.z];
        float2 u3 = *(const float2*)&vv[2 * kk.w];
        float4 r;
        r.x = __fdividef(u0.x, u0.y);
        r.y = __fdividef(u1.x, u1.y);
        r.z = __fdividef(u2.x, u2.y);
        r.w = __fdividef(u3.x, u3.y);
        ((float4*)ob)[idx] = r;
    }
}

extern "C" void kernel_launch(void* const* d_in, const int* in_sizes, int n_in,
                              void* d_out, int out_size, void* d_ws, size_t ws_size,
                              hipStream_t stream) {
    const float* feat          = (const float*)d_in[0];
    const float* embed         = (const float*)d_in[1];
    const int*   sorted_index  = (const int*)d_in[2];
    const int*   sorted_parent = (const int*)d_in[3];
    const int*   node_level    = (const int*)d_in[4];
    float* out = (float*)d_out;

    char* ws = (char*)d_ws;
    const size_t A = (size_t)BB * VV * 4;        // 64 KB
    int*   gi    = (int*)(ws);                   // 64 KB
    int*   gp    = (int*)(ws + A);               // 64 KB
    int*   giInv = (int*)(ws + 2 * A);           // 64 KB
    int*   pw    = (int*)(ws + 3 * A);           // 128 KB
    int*   offs  = (int*)(ws + 5 * A);           // 256 B (pad to 4 KB)
    float* et    = (float*)(ws + 5 * A + 4096);  // 4 MB
    const size_t need_et = 5 * A + 4096 + (size_t)BB * VV * CE * 4;
    int use_et = (ws_size >= need_et) ? 1 : 0;

    int prep_blocks = use_et ? (BB + BB * 64) : BB;
    prep_kernel<<<prep_blocks, 256, 0, stream>>>(
        embed, sorted_index, sorted_parent, node_level,
        gi, gp, giInv, pw, offs, et, use_et);

    if (use_et)
        weight_t_kernel<<<(BB * VV) / 4, 256, 0, stream>>>(et, gi, gp, pw);
    else
        weight_s_kernel<<<(BB * VV) / 4, 256, 0, stream>>>(embed, gi, gp, pw);

    tree_kernel<<<BB * CC, 256, 0, stream>>>(feat, giInv, pw, offs, out);
}